// Round 2
// baseline (105.529 us; speedup 1.0000x reference)
//
#include <hip/hip_runtime.h>

// Two-scalar fused loss over 8192x4096 f32 arrays:
//   out[0] = sum( (|y|>=mu) + (0<|y|<mu)*|y|/mu ) / 8192
//   out[1] = sum( (y_echo/22.8 - f)^2 ) / 8192
// Memory-bound streaming reduction: 3 arrays x 134MB read, 8B written.
// Round 1 lesson: VGPR=16 -> no loads in flight across iterations.
// Fix: 4x unroll, batch 12 float4 loads before consuming (ILP).

#define ECHO_SCALE 22.8f
#define N_ROWS 8192.0f

__global__ void init_out_kernel(float* out) {
    if (threadIdx.x < 2) out[threadIdx.x] = 0.0f;
}

__device__ __forceinline__ void consume(const float4& vy, const float4& ve,
                                        const float4& vf, float inv_mu,
                                        float inv_echo, float& s0, float& s1) {
    // pseudo_l0: min(|y|/mu, 1) == hard indicator + linear ramp (branchless)
    s0 += fminf(fabsf(vy.x) * inv_mu, 1.0f);
    s0 += fminf(fabsf(vy.y) * inv_mu, 1.0f);
    s0 += fminf(fabsf(vy.z) * inv_mu, 1.0f);
    s0 += fminf(fabsf(vy.w) * inv_mu, 1.0f);
    float dx = ve.x * inv_echo - vf.x;
    float dy = ve.y * inv_echo - vf.y;
    float dz = ve.z * inv_echo - vf.z;
    float dw = ve.w * inv_echo - vf.w;
    s1 += dx * dx;
    s1 += dy * dy;
    s1 += dz * dz;
    s1 += dw * dw;
}

__global__ __launch_bounds__(256) void loss_kernel(
    const float4* __restrict__ y,
    const float4* __restrict__ ye,
    const float4* __restrict__ f,
    const float* __restrict__ mu_ptr,
    float* __restrict__ out,
    long long n4)
{
    const float mu = mu_ptr[0];
    const float inv_mu = 1.0f / mu;
    const float inv_echo = 1.0f / ECHO_SCALE;

    // split accumulators to shorten dependency chains
    float s0a = 0.0f, s0b = 0.0f, s0c = 0.0f, s0d = 0.0f;
    float s1a = 0.0f, s1b = 0.0f, s1c = 0.0f, s1d = 0.0f;

    const long long idx = (long long)blockIdx.x * blockDim.x + threadIdx.x;
    const long long stride = (long long)gridDim.x * blockDim.x;

    long long i = idx;
    for (; i + 3 * stride < n4; i += 4 * stride) {
        // issue all 12 loads before consuming any (keeps them in flight)
        float4 vy0 = y[i];
        float4 vy1 = y[i + stride];
        float4 vy2 = y[i + 2 * stride];
        float4 vy3 = y[i + 3 * stride];
        float4 ve0 = ye[i];
        float4 ve1 = ye[i + stride];
        float4 ve2 = ye[i + 2 * stride];
        float4 ve3 = ye[i + 3 * stride];
        float4 vf0 = f[i];
        float4 vf1 = f[i + stride];
        float4 vf2 = f[i + 2 * stride];
        float4 vf3 = f[i + 3 * stride];

        consume(vy0, ve0, vf0, inv_mu, inv_echo, s0a, s1a);
        consume(vy1, ve1, vf1, inv_mu, inv_echo, s0b, s1b);
        consume(vy2, ve2, vf2, inv_mu, inv_echo, s0c, s1c);
        consume(vy3, ve3, vf3, inv_mu, inv_echo, s0d, s1d);
    }
    for (; i < n4; i += stride) {
        float4 vy = y[i];
        float4 ve = ye[i];
        float4 vf = f[i];
        consume(vy, ve, vf, inv_mu, inv_echo, s0a, s1a);
    }

    float s0 = (s0a + s0b) + (s0c + s0d);
    float s1 = (s1a + s1b) + (s1c + s1d);

    // wave-64 butterfly reduce
    #pragma unroll
    for (int off = 32; off > 0; off >>= 1) {
        s0 += __shfl_down(s0, off, 64);
        s1 += __shfl_down(s1, off, 64);
    }

    __shared__ float l0[4];
    __shared__ float l1[4];
    const int wave = threadIdx.x >> 6;
    const int lane = threadIdx.x & 63;
    if (lane == 0) { l0[wave] = s0; l1[wave] = s1; }
    __syncthreads();

    if (threadIdx.x == 0) {
        float t0 = 0.0f, t1 = 0.0f;
        #pragma unroll
        for (int w = 0; w < 4; ++w) { t0 += l0[w]; t1 += l1[w]; }
        atomicAdd(&out[0], t0 * (1.0f / N_ROWS));
        atomicAdd(&out[1], t1 * (1.0f / N_ROWS));
    }
}

extern "C" void kernel_launch(void* const* d_in, const int* in_sizes, int n_in,
                              void* d_out, int out_size, void* d_ws, size_t ws_size,
                              hipStream_t stream) {
    const float4* y  = (const float4*)d_in[0];
    const float4* ye = (const float4*)d_in[1];
    const float4* f  = (const float4*)d_in[2];
    const float* mu  = (const float*)d_in[3];
    float* out = (float*)d_out;

    const long long n  = (long long)in_sizes[0];  // 8192*4096, divisible by 4
    const long long n4 = n / 4;

    init_out_kernel<<<1, 64, 0, stream>>>(out);

    const int block = 256;
    int grid = 2048;  // 256 CUs x 8 blocks; grid-stride covers the rest
    long long needed = (n4 + block - 1) / block;
    if (needed < grid) grid = (int)needed;

    loss_kernel<<<grid, block, 0, stream>>>(y, ye, f, mu, out, n4);
}

// Round 3
// 98.198 us; speedup vs baseline: 1.0747x; 1.0747x over previous
//
#include <hip/hip_runtime.h>

// Two-scalar fused loss over 8192x4096 f32 arrays:
//   out[0] = sum( (|y|>=mu) + (0<|y|<mu)*|y|/mu ) / 8192   [== min(|y|/mu,1)]
//   out[1] = sum( (y_echo/22.8 - f)^2 ) / 8192
// Memory-bound streaming reduction: 3 arrays x 134MB read, 8B written.
// Round 2 lesson: grid-stride (8 MiB hops) leaves DRAM row locality on the
// floor (~3.8 TB/s total). Fix: block-contiguous panels, sequential sweep.

#define ECHO_SCALE 22.8f
#define N_ROWS 8192.0f

__global__ void init_out_kernel(float* out) {
    if (threadIdx.x < 2) out[threadIdx.x] = 0.0f;
}

__device__ __forceinline__ void consume(const float4& vy, const float4& ve,
                                        const float4& vf, float inv_mu,
                                        float inv_echo, float& s0, float& s1) {
    s0 += fminf(fabsf(vy.x) * inv_mu, 1.0f);
    s0 += fminf(fabsf(vy.y) * inv_mu, 1.0f);
    s0 += fminf(fabsf(vy.z) * inv_mu, 1.0f);
    s0 += fminf(fabsf(vy.w) * inv_mu, 1.0f);
    float dx = ve.x * inv_echo - vf.x;
    float dy = ve.y * inv_echo - vf.y;
    float dz = ve.z * inv_echo - vf.z;
    float dw = ve.w * inv_echo - vf.w;
    s1 += dx * dx;
    s1 += dy * dy;
    s1 += dz * dz;
    s1 += dw * dw;
}

__global__ __launch_bounds__(256) void loss_kernel(
    const float4* __restrict__ y,
    const float4* __restrict__ ye,
    const float4* __restrict__ f,
    const float* __restrict__ mu_ptr,
    float* __restrict__ out,
    long long n4)
{
    const float mu = mu_ptr[0];
    const float inv_mu = 1.0f / mu;
    const float inv_echo = 1.0f / ECHO_SCALE;

    float s0a = 0.0f, s0b = 0.0f;
    float s1a = 0.0f, s1b = 0.0f;

    // Block-contiguous panel: each block sweeps a sequential slice so the
    // DRAM-side stream is contiguous (4 KiB/step/array, row-buffer friendly).
    const long long per_block = (n4 + gridDim.x - 1) / gridDim.x;
    const long long start = (long long)blockIdx.x * per_block;
    long long end = start + per_block;
    if (end > n4) end = n4;

    const int tid = threadIdx.x;
    const long long bs = blockDim.x;  // 256

    long long i = start + tid;
    for (; i + bs < end; i += 2 * bs) {
        // 6 loads in flight before any consume
        float4 vy0 = y[i];
        float4 vy1 = y[i + bs];
        float4 ve0 = ye[i];
        float4 ve1 = ye[i + bs];
        float4 vf0 = f[i];
        float4 vf1 = f[i + bs];
        consume(vy0, ve0, vf0, inv_mu, inv_echo, s0a, s1a);
        consume(vy1, ve1, vf1, inv_mu, inv_echo, s0b, s1b);
    }
    for (; i < end; i += bs) {
        float4 vy = y[i];
        float4 ve = ye[i];
        float4 vf = f[i];
        consume(vy, ve, vf, inv_mu, inv_echo, s0a, s1a);
    }

    float s0 = s0a + s0b;
    float s1 = s1a + s1b;

    // wave-64 butterfly reduce
    #pragma unroll
    for (int off = 32; off > 0; off >>= 1) {
        s0 += __shfl_down(s0, off, 64);
        s1 += __shfl_down(s1, off, 64);
    }

    __shared__ float l0[4];
    __shared__ float l1[4];
    const int wave = threadIdx.x >> 6;
    const int lane = threadIdx.x & 63;
    if (lane == 0) { l0[wave] = s0; l1[wave] = s1; }
    __syncthreads();

    if (threadIdx.x == 0) {
        float t0 = 0.0f, t1 = 0.0f;
        #pragma unroll
        for (int w = 0; w < 4; ++w) { t0 += l0[w]; t1 += l1[w]; }
        atomicAdd(&out[0], t0 * (1.0f / N_ROWS));
        atomicAdd(&out[1], t1 * (1.0f / N_ROWS));
    }
}

extern "C" void kernel_launch(void* const* d_in, const int* in_sizes, int n_in,
                              void* d_out, int out_size, void* d_ws, size_t ws_size,
                              hipStream_t stream) {
    const float4* y  = (const float4*)d_in[0];
    const float4* ye = (const float4*)d_in[1];
    const float4* f  = (const float4*)d_in[2];
    const float* mu  = (const float*)d_in[3];
    float* out = (float*)d_out;

    const long long n  = (long long)in_sizes[0];  // 8192*4096, divisible by 4
    const long long n4 = n / 4;

    init_out_kernel<<<1, 64, 0, stream>>>(out);

    const int block = 256;
    int grid = 2048;  // 256 CUs x 8 blocks; each block sweeps n4/2048 elements
    long long needed = (n4 + block - 1) / block;
    if (needed < grid) grid = (int)needed;

    loss_kernel<<<grid, block, 0, stream>>>(y, ye, f, mu, out, n4);
}

// Round 5
// 92.766 us; speedup vs baseline: 1.1376x; 1.0586x over previous
//
#include <hip/hip_runtime.h>

// Two-scalar fused loss over 8192x4096 f32 arrays:
//   out[0] = sum( (|y|>=mu) + (0<|y|<mu)*|y|/mu ) / 8192   [== min(|y|/mu,1)]
//   out[1] = sum( (y_echo/22.8 - f)^2 ) / 8192
// Memory-bound streaming reduction: 3 arrays x 134MB read, 8B written.
// Round 3 lesson: cache-resident replays were NOT faster -> L3 array BW is
// the ceiling (hit-reads + miss-fills ~400MB/dispatch at ~4 TB/s). Fix:
// non-temporal loads (nt flag) -> no L3 allocation, stream pure HBM path.
// Round 4 fix: __builtin_nontemporal_load needs a native vector type, not
// HIP_vector_type<float,4> -- use ext_vector_type(4).

#define ECHO_SCALE 22.8f
#define N_ROWS 8192.0f

typedef float fx4 __attribute__((ext_vector_type(4)));

__global__ void init_out_kernel(float* out) {
    if (threadIdx.x < 2) out[threadIdx.x] = 0.0f;
}

__device__ __forceinline__ fx4 ldnt(const fx4* p) {
    return __builtin_nontemporal_load(p);
}

__device__ __forceinline__ void consume(const fx4& vy, const fx4& ve,
                                        const fx4& vf, float inv_mu,
                                        float inv_echo, float& s0, float& s1) {
    s0 += fminf(fabsf(vy.x) * inv_mu, 1.0f);
    s0 += fminf(fabsf(vy.y) * inv_mu, 1.0f);
    s0 += fminf(fabsf(vy.z) * inv_mu, 1.0f);
    s0 += fminf(fabsf(vy.w) * inv_mu, 1.0f);
    float dx = ve.x * inv_echo - vf.x;
    float dy = ve.y * inv_echo - vf.y;
    float dz = ve.z * inv_echo - vf.z;
    float dw = ve.w * inv_echo - vf.w;
    s1 += dx * dx;
    s1 += dy * dy;
    s1 += dz * dz;
    s1 += dw * dw;
}

__global__ __launch_bounds__(256) void loss_kernel(
    const fx4* __restrict__ y,
    const fx4* __restrict__ ye,
    const fx4* __restrict__ f,
    const float* __restrict__ mu_ptr,
    float* __restrict__ out,
    long long n4)
{
    const float mu = mu_ptr[0];
    const float inv_mu = 1.0f / mu;
    const float inv_echo = 1.0f / ECHO_SCALE;

    float s0a = 0.0f, s0b = 0.0f;
    float s1a = 0.0f, s1b = 0.0f;

    // Block-contiguous panel sweep (sequential DRAM streams per block).
    const long long per_block = (n4 + gridDim.x - 1) / gridDim.x;
    const long long start = (long long)blockIdx.x * per_block;
    long long end = start + per_block;
    if (end > n4) end = n4;

    const int tid = threadIdx.x;
    const long long bs = blockDim.x;  // 256

    long long i = start + tid;
    for (; i + bs < end; i += 2 * bs) {
        // 6 non-temporal loads in flight before any consume
        fx4 vy0 = ldnt(&y[i]);
        fx4 vy1 = ldnt(&y[i + bs]);
        fx4 ve0 = ldnt(&ye[i]);
        fx4 ve1 = ldnt(&ye[i + bs]);
        fx4 vf0 = ldnt(&f[i]);
        fx4 vf1 = ldnt(&f[i + bs]);
        consume(vy0, ve0, vf0, inv_mu, inv_echo, s0a, s1a);
        consume(vy1, ve1, vf1, inv_mu, inv_echo, s0b, s1b);
    }
    for (; i < end; i += bs) {
        fx4 vy = ldnt(&y[i]);
        fx4 ve = ldnt(&ye[i]);
        fx4 vf = ldnt(&f[i]);
        consume(vy, ve, vf, inv_mu, inv_echo, s0a, s1a);
    }

    float s0 = s0a + s0b;
    float s1 = s1a + s1b;

    // wave-64 butterfly reduce
    #pragma unroll
    for (int off = 32; off > 0; off >>= 1) {
        s0 += __shfl_down(s0, off, 64);
        s1 += __shfl_down(s1, off, 64);
    }

    __shared__ float l0[4];
    __shared__ float l1[4];
    const int wave = threadIdx.x >> 6;
    const int lane = threadIdx.x & 63;
    if (lane == 0) { l0[wave] = s0; l1[wave] = s1; }
    __syncthreads();

    if (threadIdx.x == 0) {
        float t0 = 0.0f, t1 = 0.0f;
        #pragma unroll
        for (int w = 0; w < 4; ++w) { t0 += l0[w]; t1 += l1[w]; }
        atomicAdd(&out[0], t0 * (1.0f / N_ROWS));
        atomicAdd(&out[1], t1 * (1.0f / N_ROWS));
    }
}

extern "C" void kernel_launch(void* const* d_in, const int* in_sizes, int n_in,
                              void* d_out, int out_size, void* d_ws, size_t ws_size,
                              hipStream_t stream) {
    const fx4* y  = (const fx4*)d_in[0];
    const fx4* ye = (const fx4*)d_in[1];
    const fx4* f  = (const fx4*)d_in[2];
    const float* mu  = (const float*)d_in[3];
    float* out = (float*)d_out;

    const long long n  = (long long)in_sizes[0];  // 8192*4096, divisible by 4
    const long long n4 = n / 4;

    init_out_kernel<<<1, 64, 0, stream>>>(out);

    const int block = 256;
    int grid = 2048;  // 256 CUs x 8 blocks; each block sweeps n4/2048 elements
    long long needed = (n4 + block - 1) / block;
    if (needed < grid) grid = (int)needed;

    loss_kernel<<<grid, block, 0, stream>>>(y, ye, f, mu, out, n4);
}